// Round 1
// baseline (294.262 us; speedup 1.0000x reference)
//
#include <hip/hip_runtime.h>

typedef _Float16 f16;
typedef _Float16 f16x4 __attribute__((ext_vector_type(4)));
typedef _Float16 f16x8 __attribute__((ext_vector_type(8)));
typedef float f32x4 __attribute__((ext_vector_type(4)));

#define ALPHA 0.2f
#define NN 8192
#define DD 256

// ---------------- K1: Wh = h @ W (f32), plus WhT in fp16 ----------------
// grid 256 blocks x 256 thr; each block: 32 rows x 256 cols, K=256.
__global__ __launch_bounds__(256) void k1_gemm(const float* __restrict__ h,
                                               const float* __restrict__ W,
                                               float* __restrict__ Wh,
                                               f16* __restrict__ WhT) {
    __shared__ float h_lds[32][256];
    const int t  = threadIdx.x;
    const int i0 = blockIdx.x * 32;

    #pragma unroll
    for (int p = 0; p < 8; ++p) {
        int idx = p * 256 + t;          // 2048 float4 chunks
        int r = idx >> 6;
        int c = (idx & 63) << 2;
        *(float4*)&h_lds[r][c] = *(const float4*)&h[(i0 + r) * DD + c];
    }
    __syncthreads();

    const int c0 = (t & 63) << 2;       // 64 col-groups of 4
    const int r0 = (t >> 6) << 3;       // 4 row-groups of 8
    float acc[8][4];
    #pragma unroll
    for (int r = 0; r < 8; ++r)
        #pragma unroll
        for (int c = 0; c < 4; ++c) acc[r][c] = 0.f;

    for (int k = 0; k < DD; ++k) {
        float4 w4 = *(const float4*)&W[k * DD + c0];
        #pragma unroll
        for (int r = 0; r < 8; ++r) {
            float hv = h_lds[r0 + r][k];
            acc[r][0] = fmaf(hv, w4.x, acc[r][0]);
            acc[r][1] = fmaf(hv, w4.y, acc[r][1]);
            acc[r][2] = fmaf(hv, w4.z, acc[r][2]);
            acc[r][3] = fmaf(hv, w4.w, acc[r][3]);
        }
    }

    #pragma unroll
    for (int r = 0; r < 8; ++r) {
        float4 v; v.x = acc[r][0]; v.y = acc[r][1]; v.z = acc[r][2]; v.w = acc[r][3];
        *(float4*)&Wh[(i0 + r0 + r) * DD + c0] = v;
    }
    // transposed fp16 V: WhT[n][i], 8 consecutive rows per col -> 16B store
    #pragma unroll
    for (int c = 0; c < 4; ++c) {
        f16x8 v;
        #pragma unroll
        for (int r = 0; r < 8; ++r) v[r] = (f16)acc[r][c];
        *(f16x8*)&WhT[(c0 + c) * NN + i0 + r0] = v;
    }
}

// ---------------- K2: Wh1 = Wh@a1, Wh2 = Wh@a2, max(Wh2) ----------------
__global__ __launch_bounds__(256) void k2_rowdot(const float* __restrict__ Wh,
                                                 const float* __restrict__ a,
                                                 float* __restrict__ Wh1,
                                                 float* __restrict__ Wh2,
                                                 unsigned* __restrict__ maxkey) {
    const int lane = threadIdx.x & 63;
    const int wave = threadIdx.x >> 6;
    const int i = blockIdx.x * 4 + wave;

    float4 v  = *(const float4*)&Wh[i * DD + lane * 4];
    float4 a1 = *(const float4*)&a[lane * 4];
    float4 a2 = *(const float4*)&a[DD + lane * 4];
    float s1 = v.x * a1.x + v.y * a1.y + v.z * a1.z + v.w * a1.w;
    float s2 = v.x * a2.x + v.y * a2.y + v.z * a2.z + v.w * a2.w;
    #pragma unroll
    for (int off = 32; off; off >>= 1) {
        s1 += __shfl_down(s1, off);
        s2 += __shfl_down(s2, off);
    }
    if (lane == 0) {
        Wh1[i] = s1;
        Wh2[i] = s2;
        unsigned u = __float_as_uint(s2);
        u = (u & 0x80000000u) ? ~u : (u | 0x80000000u);   // monotone key
        atomicMax(maxkey, u);
    }
}

// ---------------- K3: fused masked softmax + PV ----------------
// grid 256 blocks x 512 thr (8 waves). Block: 32 rows, loop j in tiles of 64.
// P[32][64] fp16 in XOR-swizzled LDS; V tile WhT[256][64] fp16 in swizzled LDS.
// Wave w computes out cols [w*32, w*32+32).
__global__ __launch_bounds__(512) void k3_attn(const int* __restrict__ adj,
                                               const f16* __restrict__ WhT,
                                               const float* __restrict__ Wh1,
                                               const float* __restrict__ Wh2,
                                               const unsigned* __restrict__ maxkey,
                                               float* __restrict__ out) {
    __shared__ __align__(16) unsigned char p_lds[32 * 128];    // 4 KB
    __shared__ __align__(16) unsigned char v_lds[256 * 128];   // 32 KB
    __shared__ float s_lds[32];

    const int t    = threadIdx.x;
    const int lane = t & 63;
    const int w    = t >> 6;
    const int i0   = blockIdx.x * 32;

    unsigned mk = *maxkey;
    float maxW2 = __uint_as_float((mk & 0x80000000u) ? (mk & 0x7fffffffu) : ~mk);

    // P-compute mapping: thread t -> row pr (0..31), cols pc..pc+3 (of 64)
    const int pr = t >> 4;
    const int pc = (t & 15) << 2;
    const float wh1_r = Wh1[i0 + pr];
    float marg = wh1_r + maxW2;
    const float m_r = (marg > 0.f) ? marg : ALPHA * marg;   // exact row shift, P <= 1

    // V staging mapping: thread t -> WhT rows nb, nb+64, nb+128, nb+192; chunk ch
    const int nb = t >> 3;
    const int ch = t & 7;

    const int pbyte = pr * 128 + ((pc << 1) ^ ((pr & 7) << 4));        // swizzled 8B slot
    const int vbyte = nb * 128 + ((ch << 4) ^ ((nb & 7) << 4));        // swizzled 16B slot
    const int adj_base = (i0 + pr) * NN + pc;
    const int wht_base = nb * NN + (ch << 3);

    f32x4 acc00 = {0.f, 0.f, 0.f, 0.f};
    f32x4 acc01 = {0.f, 0.f, 0.f, 0.f};
    f32x4 acc10 = {0.f, 0.f, 0.f, 0.f};
    f32x4 acc11 = {0.f, 0.f, 0.f, 0.f};
    float s_acc = 0.f;

    // prologue prefetch (tile 0)
    int4   adj_v = *(const int4*)&adj[adj_base];
    float4 wh2_v = *(const float4*)&Wh2[pc];
    int4 vv0 = *(const int4*)&WhT[wht_base];
    int4 vv1 = *(const int4*)&WhT[wht_base + 64 * NN];
    int4 vv2 = *(const int4*)&WhT[wht_base + 128 * NN];
    int4 vv3 = *(const int4*)&WhT[wht_base + 192 * NN];

    for (int jt = 0; jt < 128; ++jt) {
        // ---- P compute from prefetched regs ----
        float e0 = wh1_r + wh2_v.x; e0 = (e0 > 0.f) ? e0 : ALPHA * e0;
        float e1 = wh1_r + wh2_v.y; e1 = (e1 > 0.f) ? e1 : ALPHA * e1;
        float e2 = wh1_r + wh2_v.z; e2 = (e2 > 0.f) ? e2 : ALPHA * e2;
        float e3 = wh1_r + wh2_v.w; e3 = (e3 > 0.f) ? e3 : ALPHA * e3;
        float p0 = (adj_v.x > 0) ? __expf(e0 - m_r) : 0.f;
        float p1 = (adj_v.y > 0) ? __expf(e1 - m_r) : 0.f;
        float p2 = (adj_v.z > 0) ? __expf(e2 - m_r) : 0.f;
        float p3 = (adj_v.w > 0) ? __expf(e3 - m_r) : 0.f;
        s_acc += (p0 + p1) + (p2 + p3);
        f16x4 pk; pk[0] = (f16)p0; pk[1] = (f16)p1; pk[2] = (f16)p2; pk[3] = (f16)p3;
        *(f16x4*)&p_lds[pbyte] = pk;

        // ---- V tile regs -> swizzled LDS ----
        *(int4*)&v_lds[vbyte]         = vv0;
        *(int4*)&v_lds[vbyte + 8192]  = vv1;
        *(int4*)&v_lds[vbyte + 16384] = vv2;
        *(int4*)&v_lds[vbyte + 24576] = vv3;

        // ---- prefetch tile jt+1 ----
        if (jt < 127) {
            int j1 = (jt + 1) << 6;
            adj_v = *(const int4*)&adj[adj_base + j1];
            wh2_v = *(const float4*)&Wh2[j1 + pc];
            vv0 = *(const int4*)&WhT[wht_base + j1];
            vv1 = *(const int4*)&WhT[wht_base + 64 * NN + j1];
            vv2 = *(const int4*)&WhT[wht_base + 128 * NN + j1];
            vv3 = *(const int4*)&WhT[wht_base + 192 * NN + j1];
        }
        __syncthreads();

        // ---- MFMA: wave w does n-chunk [w*32, w*32+32) ----
        #pragma unroll
        for (int kt = 0; kt < 2; ++kt) {
            int kbyte = (kt << 6) + ((lane >> 4) << 4);
            int ar0 = lane & 15;
            int ar1 = 16 + (lane & 15);
            f16x8 a0 = *(const f16x8*)&p_lds[ar0 * 128 + (kbyte ^ ((ar0 & 7) << 4))];
            f16x8 a1 = *(const f16x8*)&p_lds[ar1 * 128 + (kbyte ^ ((ar1 & 7) << 4))];
            int br0 = (w << 5) + (lane & 15);
            int br1 = br0 + 16;
            f16x8 b0 = *(const f16x8*)&v_lds[br0 * 128 + (kbyte ^ ((br0 & 7) << 4))];
            f16x8 b1 = *(const f16x8*)&v_lds[br1 * 128 + (kbyte ^ ((br1 & 7) << 4))];
            acc00 = __builtin_amdgcn_mfma_f32_16x16x32_f16(a0, b0, acc00, 0, 0, 0);
            acc01 = __builtin_amdgcn_mfma_f32_16x16x32_f16(a0, b1, acc01, 0, 0, 0);
            acc10 = __builtin_amdgcn_mfma_f32_16x16x32_f16(a1, b0, acc10, 0, 0, 0);
            acc11 = __builtin_amdgcn_mfma_f32_16x16x32_f16(a1, b1, acc11, 0, 0, 0);
        }
        __syncthreads();
    }

    // ---- row-sum reduce (16 lanes per row, wave-local rows) ----
    s_acc += __shfl_xor(s_acc, 1);
    s_acc += __shfl_xor(s_acc, 2);
    s_acc += __shfl_xor(s_acc, 4);
    s_acc += __shfl_xor(s_acc, 8);
    if ((lane & 15) == 0) s_lds[pr] = s_acc;
    __syncthreads();

    // ---- epilogue: normalize + ELU + store ----
    #pragma unroll
    for (int mt = 0; mt < 2; ++mt) {
        #pragma unroll
        for (int nt = 0; nt < 2; ++nt) {
            f32x4 av = (mt == 0) ? ((nt == 0) ? acc00 : acc01)
                                 : ((nt == 0) ? acc10 : acc11);
            #pragma unroll
            for (int q = 0; q < 4; ++q) {
                int il = (mt << 4) + ((lane >> 4) << 2) + q;     // C/D: row=(lane>>4)*4+reg
                int n  = (w << 5) + (nt << 4) + (lane & 15);     // C/D: col=lane&15
                float v = av[q] / s_lds[il];
                v = (v > 0.f) ? v : (__expf(v) - 1.f);           // ELU(alpha=1)
                out[(i0 + il) * DD + n] = v;
            }
        }
    }
}

extern "C" void kernel_launch(void* const* d_in, const int* in_sizes, int n_in,
                              void* d_out, int out_size, void* d_ws, size_t ws_size,
                              hipStream_t stream) {
    const float* h   = (const float*)d_in[0];
    const int*   adj = (const int*)d_in[1];
    const float* W   = (const float*)d_in[2];
    const float* a   = (const float*)d_in[3];
    float* out = (float*)d_out;

    char* ws = (char*)d_ws;
    float*    Wh     = (float*)ws;                     // 8 MB
    f16*      WhT    = (f16*)(ws + 8388608);           // 4 MB
    float*    Wh1    = (float*)(ws + 12582912);        // 32 KB
    float*    Wh2    = (float*)(ws + 12615680);        // 32 KB
    unsigned* maxkey = (unsigned*)(ws + 12648448);     // 4 B

    hipMemsetAsync(maxkey, 0, 4, stream);
    k1_gemm<<<dim3(256), dim3(256), 0, stream>>>(h, W, Wh, WhT);
    k2_rowdot<<<dim3(2048), dim3(256), 0, stream>>>(Wh, a, Wh1, Wh2, maxkey);
    k3_attn<<<dim3(256), dim3(512), 0, stream>>>(adj, WhT, Wh1, Wh2, maxkey, out);
}